// Round 10
// baseline (230.307 us; speedup 1.0000x reference)
//
#include <hip/hip_runtime.h>
#include <math.h>

// B=32, S=4096, D=256  (fp32). MAX_LEN=5000.
// out[b,s,d] = nodes[b,s,d] + (s <= num_nodes[b] ? pe[(s-num_nodes[b]) mod 5000, d] : 0)
// pe[p, 2k] = sin(p * div[k]), pe[p, 2k+1] = cos(p * div[k]), div[k] = exp2(-log2(1e4)*2k/256)
//
// Evidence ledger (dispatch = headline - ~155 us harness poison fills,
// calibrated r5-r9; fills themselves: 512 MiB @ 6.7-6.8 TB/s, write-only):
//  - r7 flat 32768 blk, 1xf4/thread, NT/NT:        ~65 us (4.1 TB/s)
//  - r8 same, reg/reg:                             ~69 us
//  - r9 flat 8192 blk, 4xf4 contig, branch-free,
//    NT/NT:                                        ~66 us
//  - r5/r6 persistent 2048 blk, 8MB-stride, reg/NT: 85 us (FETCH=64MB!)
//  - roofline: 268 MB @ 6.3 TB/s                  ~43 us
// Falsified: CP dispatch rate (8k==32k blocks), MLP/load-cluster, NT tax,
// occupancy x MLP. Composition doesn't matter; the gap is in the memory path.
//
// This round, ONE variable vs r9: load policy NT -> REGULAR (allocating).
// r5/r6 proved input can stay half-LLC-resident across iterations (FETCH
// 64 MB) when loads allocate and stores are NT (NT stores don't churn the
// LLC; r8's regular stores did). reg-load + NT-store on the FLAT grid is
// the one untested policy cell, and the only theory left standing.
// Predict: 50-60 us if LLC residency pays; ~65 us -> matrix exhausted,
// local mixed-stream ceiling ~4.2 TB/s, argue roofline next round.

typedef float v4f __attribute__((ext_vector_type(4)));

#define BLOCK 256
#define UNROLL 4

__device__ __forceinline__ v4f pe_add(v4f v, int idx, int nn, float f0, float f1) {
    const int s = (idx >> 6) & 4095;       // sequence position (wave-uniform)
    int r = s - nn;                        // no-branch Python mod: r in (-4096, 4096)
    int p = (r < 0) ? r + 5000 : r;        // v_cndmask
    const float pf = (float)p;
    float r0 = pf * f0;  r0 -= floorf(r0); // [0,1) revolutions
    float r1 = pf * f1;  r1 -= floorf(r1);
    const float m = (s <= nn) ? 1.0f : 0.0f;  // v_cndmask mask, no divergence
    v.x = fmaf(m, __builtin_amdgcn_sinf(r0), v.x);  // v_sin_f32: sin(2*pi*r0)
    v.y = fmaf(m, __builtin_amdgcn_cosf(r0), v.y);
    v.z = fmaf(m, __builtin_amdgcn_sinf(r1), v.z);
    v.w = fmaf(m, __builtin_amdgcn_cosf(r1), v.w);
    return v;
}

template <bool EXACT>
__global__ __launch_bounds__(BLOCK) void rpe_kernel(const float* __restrict__ nodes,
                                                    const int* __restrict__ num_nodes,
                                                    float* __restrict__ out,
                                                    const int total4) {
    const int base = blockIdx.x * (BLOCK * UNROLL) + threadIdx.x;

    // d4 identical for all 4 sweeps (sweep stride 256 == 0 mod 64): exp2 once.
    const int d4 = base & 63;
    const float cexp   = -0.051905126482062035f;  // -log2(10000)/256
    const float inv2pi = 0.15915494309189535f;
    const float f0 = exp2f(cexp * (float)(4 * d4)) * inv2pi;
    const float f1 = exp2f(cexp * (float)(4 * d4 + 2)) * inv2pi;

    const v4f* __restrict__ in4  = reinterpret_cast<const v4f*>(nodes);
    v4f* __restrict__       out4 = reinterpret_cast<v4f*>(out);

    if (EXACT) {
        const int i0 = base;
        const int i1 = base + BLOCK;
        const int i2 = base + 2 * BLOCK;
        const int i3 = base + 3 * BLOCK;

        // 4-load cluster, REGULAR loads (allocate in LLC; input is 134 MB
        // < 256 MiB LLC and r5/r6 proved half survives the poison fills).
        v4f v0 = in4[i0];
        v4f v1 = in4[i1];
        v4f v2 = in4[i2];
        v4f v3 = in4[i3];
        // b = idx>>18 wave-uniform; readfirstlane -> one s_load per wave each.
        const int n0 = num_nodes[__builtin_amdgcn_readfirstlane(i0 >> 18)];
        const int n1 = num_nodes[__builtin_amdgcn_readfirstlane(i1 >> 18)];
        const int n2 = num_nodes[__builtin_amdgcn_readfirstlane(i2 >> 18)];
        const int n3 = num_nodes[__builtin_amdgcn_readfirstlane(i3 >> 18)];

        v0 = pe_add(v0, i0, n0, f0, f1);
        v1 = pe_add(v1, i1, n1, f0, f1);
        v2 = pe_add(v2, i2, n2, f0, f1);
        v3 = pe_add(v3, i3, n3, f0, f1);

        // NT stores: out is never re-read; do NOT evict the input's LLC lines.
        __builtin_nontemporal_store(v0, out4 + i0);
        __builtin_nontemporal_store(v1, out4 + i1);
        __builtin_nontemporal_store(v2, out4 + i2);
        __builtin_nontemporal_store(v3, out4 + i3);
    } else {
        #pragma unroll
        for (int j = 0; j < UNROLL; ++j) {
            const int idx = base + j * BLOCK;
            if (idx < total4) {
                v4f v = in4[idx];
                const int nn = num_nodes[__builtin_amdgcn_readfirstlane(idx >> 18)];
                v = pe_add(v, idx, nn, f0, f1);
                __builtin_nontemporal_store(v, out4 + idx);
            }
        }
    }
}

extern "C" void kernel_launch(void* const* d_in, const int* in_sizes, int n_in,
                              void* d_out, int out_size, void* d_ws, size_t ws_size,
                              hipStream_t stream) {
    const float* nodes     = (const float*)d_in[0];
    const int*   num_nodes = (const int*)d_in[1];
    float*       out       = (float*)d_out;

    // total float4 elements: 32*4096*256/4 = 8388608 = 8192 * (256*4) exactly
    const int total4 = out_size / 4;
    const int grid   = (total4 + BLOCK * UNROLL - 1) / (BLOCK * UNROLL);

    if (total4 % (BLOCK * UNROLL) == 0) {
        rpe_kernel<true><<<grid, BLOCK, 0, stream>>>(nodes, num_nodes, out, total4);
    } else {
        rpe_kernel<false><<<grid, BLOCK, 0, stream>>>(nodes, num_nodes, out, total4);
    }
}

// Round 11
// 217.647 us; speedup vs baseline: 1.0582x; 1.0582x over previous
//
#include <hip/hip_runtime.h>
#include <math.h>

// B=32, S=4096, D=256  (fp32). MAX_LEN=5000.
// out[b,s,d] = nodes[b,s,d] + (s <= num_nodes[b] ? pe[(s-num_nodes[b]) mod 5000, d] : 0)
// pe[p, 2k] = sin(p * div[k]), pe[p, 2k+1] = cos(p * div[k]), div[k] = exp2(-log2(1e4)*2k/256)
//
// Evidence ledger (dispatch = headline - ~155 us harness poison fills):
//  - r7  flat 32768 blk, NT load / NT store:    65 us  <- best
//  - r8  flat,          reg load / reg store:   69 us
//  - r10 flat,          reg load / NT store:    75 us
//  - r9  flat 4x unroll, NT/NT:                 66 us
//  - r5/6 strided persistent, reg/NT:           85 us
//  - copy roofline: 268 MB @ 6.3 TB/s:         ~43 us
// Falsified: CP dispatch rate, MLP/load-cluster, occupancy x MLP, NT tax,
// LLC input residency. All structures ~4.1 TB/s.
//
// This round, the LAST untested policy cell, with a distinct mechanism:
// NT LOAD + REGULAR STORE. A regular store retires at LLC acceptance, not
// HBM. out = 134 MB < 256 MiB LLC, and NT loads don't allocate -> zero
// capacity pressure -> LLC absorbs the whole write stream, writebacks
// deferred past kernel end. (r8 didn't show this: its reg loads allocated
// too -> 268 MB > LLC -> forced evictions during the kernel.)
// Predict: dispatch 27-45 us if absorption works; ~65-69 -> matrix closed,
// declare local ceiling next round.

typedef float v4f __attribute__((ext_vector_type(4)));

__global__ __launch_bounds__(256) void rpe_kernel(const float* __restrict__ nodes,
                                                  const int* __restrict__ num_nodes,
                                                  float* __restrict__ out,
                                                  const int total4) {
    const int tid = blockIdx.x * blockDim.x + threadIdx.x;  // one float4 per thread
    if (tid >= total4) return;                              // never taken at real shape

    const int d4 = tid & 63;           // float4 index within row (64 per row)
    const int s  = (tid >> 6) & 4095;  // sequence position
    const int b  = tid >> 18;          // batch

    const int nn = num_nodes[b];       // wave-uniform (one wave == one row)

    // NT load: streaming read, do not allocate in LLC (keeps LLC free for
    // the write stream to be absorbed).
    v4f v = __builtin_nontemporal_load(reinterpret_cast<const v4f*>(nodes) + tid);

    if (s <= nn) {                     // wave-uniform branch
        int r = s - nn;                // r in (-4096, 0]
        int p = (r < 0) ? r + 5000 : r;  // Python mod semantics
        const float pf = (float)p;

        // f[k] = div[k] / (2*pi)  (revolutions per unit position)
        const float cexp   = -0.051905126482062035f;  // -log2(10000)/256
        const float inv2pi = 0.15915494309189535f;
        const float f0 = exp2f(cexp * (float)(4 * d4)) * inv2pi;
        const float f1 = exp2f(cexp * (float)(4 * d4 + 2)) * inv2pi;

        float r0 = pf * f0;  r0 -= floorf(r0);   // [0,1) revolutions
        float r1 = pf * f1;  r1 -= floorf(r1);

        v.x += __builtin_amdgcn_sinf(r0);   // v_sin_f32: sin(2*pi*r0)
        v.y += __builtin_amdgcn_cosf(r0);
        v.z += __builtin_amdgcn_sinf(r1);
        v.w += __builtin_amdgcn_cosf(r1);
    }

    // REGULAR store: allocate in LLC; retire at LLC acceptance. 134 MB of
    // out fits entirely in the 256 MiB LLC with no read-side pressure.
    reinterpret_cast<v4f*>(out)[tid] = v;
}

extern "C" void kernel_launch(void* const* d_in, const int* in_sizes, int n_in,
                              void* d_out, int out_size, void* d_ws, size_t ws_size,
                              hipStream_t stream) {
    const float* nodes     = (const float*)d_in[0];
    const int*   num_nodes = (const int*)d_in[1];
    float*       out       = (float*)d_out;

    // total float4 elements: 32*4096*256/4 = 8388608 -> 32768 blocks of 256
    const int total4 = out_size / 4;
    const int block  = 256;
    const int grid   = (total4 + block - 1) / block;

    rpe_kernel<<<grid, block, 0, stream>>>(nodes, num_nodes, out, total4);
}